// Round 10
// baseline (250.010 us; speedup 1.0000x reference)
//
#include <hip/hip_runtime.h>
#include <hip/hip_bf16.h>
#include <cstdint>

#define LL 256   // L
#define NN 512   // N
#define DD 256   // D
#define HH 8
#define EPSF 1e-5f
#define WGS 264  // padded LDS row stride (bf16 elems) for Wg

typedef __attribute__((ext_vector_type(8))) __bf16 bf16x8;
typedef __attribute__((ext_vector_type(4))) float f32x4;

static __device__ __forceinline__ void load_group(
    const float* __restrict__ msa, int l, int row0, int col, int kb, float4 (&buf)[16])
{
    const float* rp = msa + ((size_t)(row0 + col) * LL + l) * DD + (kb << 3);
    #pragma unroll
    for (int ks = 0; ks < 8; ++ks) {
        buf[2 * ks]     = *(const float4*)(rp + ks * 32);
        buf[2 * ks + 1] = *(const float4*)(rp + ks * 32 + 4);
    }
}

static __device__ __forceinline__ void compute_group(
    const float4 (&buf)[16], const bf16x8 (&bfr)[8], f32x4& hacc, f32x4& gacc)
{
    #pragma unroll
    for (int ks = 0; ks < 8; ++ks) {
        float4 u = buf[2 * ks], v = buf[2 * ks + 1];
        bf16x8 a;
        a[0] = (__bf16)u.x; a[1] = (__bf16)u.y; a[2] = (__bf16)u.z; a[3] = (__bf16)u.w;
        a[4] = (__bf16)v.x; a[5] = (__bf16)v.y; a[6] = (__bf16)v.z; a[7] = (__bf16)v.w;
        hacc = __builtin_amdgcn_mfma_f32_16x16x32_bf16(a, bfr[ks], hacc, 0, 0, 0);
        gacc = __builtin_amdgcn_mfma_f32_16x16x32_bf16(a, a,       gacc, 0, 0, 0);
    }
}

static __device__ __forceinline__ void store_group(
    int nloc0, int col, int kb, const f32x4& hacc, const f32x4& gacc,
    float* logits, float* sS, float* sQ)
{
    #pragma unroll
    for (int i = 0; i < 4; ++i) {
        int n = nloc0 + (kb << 2) + i;       // C/D: col=lane&15, row=kb*4+i
        if (col < HH)       logits[col * 256 + n] = hacc[i];
        else if (col == HH) sS[n] = hacc[i];
    }
    if (kb == (col >> 2)) sQ[nloc0 + col] = gacc[col & 3];   // Gram diagonal
}

__global__ __launch_bounds__(512, 2) void k_fused(
    const float* __restrict__ msa, const float* __restrict__ Wq,
    const float* __restrict__ bq, const float* __restrict__ Wk,
    const float* __restrict__ gamma, const float* __restrict__ beta,
    int* __restrict__ counters, float* __restrict__ wslog,
    float* __restrict__ out)
{
    const int bid = blockIdx.x;
    const int l = bid >> 1, half = bid & 1;
    const int tid = threadIdx.x, wave = tid >> 6, lane = tid & 63;
    const int col = lane & 15, kb = lane >> 4;

    __shared__ __align__(16) float logits[HH * 256]; // 8 KB (this half's 256 rows)
    __shared__ __align__(16) float sS[256];          // Σx̂
    __shared__ __align__(16) float sQ[256];          // Σx̂²
    __shared__ __align__(16) __bf16 WgL[16 * WGS];   // 8.25 KB
    __shared__ float lnx[DD];
    __shared__ float qv[DD];
    __shared__ float red8[8];
    __shared__ float red[HH][8];
    __shared__ float Gs[HH];
    __shared__ int amLast;

    // ---- prefetch this wave's 32 rows (2 groups) ----
    const int row0 = half * 256 + wave * 32;
    float4 A[16], B[16];
    load_group(msa, l, row0,      col, kb, A);
    load_group(msa, l, row0 + 16, col, kb, B);

    // ---------- Phase 1: Wg = gamma ⊙ (q·Wk) in LDS ----------
    {
        float x0 = (tid < DD) ? msa[(size_t)l * DD + tid] : 0.f;
        float s = x0, ss = x0 * x0;
        #pragma unroll
        for (int m = 32; m >= 1; m >>= 1) { s += __shfl_xor(s, m); ss += __shfl_xor(ss, m); }
        if (tid < DD && lane == 0) { red8[wave * 2] = s; red8[wave * 2 + 1] = ss; }
        __syncthreads();
        if (tid < DD) {
            float sm = red8[0] + red8[2] + red8[4] + red8[6];
            float sq = red8[1] + red8[3] + red8[5] + red8[7];
            float mean = sm * (1.f / DD);
            float var  = sq * (1.f / DD) - mean * mean;
            float rs   = rsqrtf(var + EPSF);
            lnx[tid] = (x0 - mean) * rs * gamma[tid] + beta[tid];
        }
        __syncthreads();
        const int r = tid & 255, hf = tid >> 8;
        float acc = 0.f;
        {
            const float4* wr = (const float4*)(Wq + (size_t)r * DD) + hf * 32;
            const float* lx = lnx + hf * 128;
            #pragma unroll 4
            for (int j = 0; j < 32; ++j) {
                float4 w4 = wr[j];
                acc += lx[4*j] * w4.x + lx[4*j+1] * w4.y + lx[4*j+2] * w4.z + lx[4*j+3] * w4.w;
            }
        }
        if (hf == 0) qv[r] = acc;
        __syncthreads();
        if (hf == 1) qv[r] = (qv[r] + acc + bq[r]) * 0.17677669529663687f;
        __syncthreads();
        const int c = tid & 255, h0 = (tid >> 8) * 4;
        const float gm = gamma[c];
        #pragma unroll
        for (int hi = 0; hi < 4; ++hi) {
            int h = h0 + hi;
            float a = 0.f;
            const float* wk = Wk + ((size_t)h * 32) * DD + c;
            #pragma unroll 8
            for (int d = 0; d < 32; ++d)
                a += qv[h * 32 + d] * wk[(size_t)d * DD];
            WgL[h * WGS + c] = (__bf16)(gm * a);
        }
        if (tid < DD) {
            WgL[8 * WGS + tid] = (__bf16)1.0f;     // ones column -> row sums
        } else {
            const int c2 = tid - 256;
            #pragma unroll
            for (int h = 9; h < 16; ++h) WgL[h * WGS + c2] = (__bf16)0.0f;
        }
        __syncthreads();
        if (wave < HH) {                           // G[h] = sum_c Wg[h][c]
            float gsum = 0.f;
            #pragma unroll
            for (int i = 0; i < 4; ++i) gsum += (float)WgL[wave * WGS + lane * 4 + i];
            #pragma unroll
            for (int m = 32; m >= 1; m >>= 1) gsum += __shfl_xor(gsum, m);
            if (lane == 0) Gs[wave] = gsum;
        }
        __syncthreads();
    }

    // ---------- B fragments ----------
    bf16x8 bfr[8];
    #pragma unroll
    for (int ks = 0; ks < 8; ++ks)
        bfr[ks] = *(const bf16x8*)&WgL[col * WGS + ks * 32 + kb * 8];

    // ---------- Main: 2 groups of 16 rows per wave (256 rows/block) ----------
    const f32x4 z = {0.f, 0.f, 0.f, 0.f};
    {
        f32x4 ha = z, ga = z;
        compute_group(A, bfr, ha, ga);
        store_group(wave * 32, col, kb, ha, ga, logits, sS, sQ);
    }
    {
        f32x4 ha = z, ga = z;
        compute_group(B, bfr, ha, ga);
        store_group(wave * 32 + 16, col, kb, ha, ga, logits, sS, sQ);
    }
    __syncthreads();

    // ---------- adjusted logits -> workspace (coalesced 16B/thread) ----------
    {
        const int n = tid & 255, hg = tid >> 8;   // thread -> (row, head-quad)
        float s = sS[n], q2 = sQ[n];
        float mean = s * (1.f / DD);
        float var  = q2 * (1.f / DD) - mean * mean;
        float rs   = rsqrtf(var + EPSF);
        float o[4];
        #pragma unroll
        for (int j = 0; j < 4; ++j) {
            int h = hg * 4 + j;
            o[j] = rs * (logits[h * 256 + n] - mean * Gs[h]);
        }
        float* wp = wslog + (((size_t)l * NN) + half * 256 + n) * HH + hg * 4;
        float4 p = {o[0], o[1], o[2], o[3]};
        *(float4*)wp = p;
    }

    // ---------- last-block-per-l softmax over all 512 n ----------
    __threadfence();
    __syncthreads();
    if (tid == 0) amLast = (atomicAdd(&counters[l], 1) == 1);
    __syncthreads();
    if (!amLast) return;
    __threadfence();

    const int n = tid;
    const float* wp = wslog + ((size_t)l * NN + n) * HH;
    float4 a4 = *(const float4*)wp, b4 = *(const float4*)(wp + 4);
    float v[8] = {a4.x, a4.y, a4.z, a4.w, b4.x, b4.y, b4.z, b4.w};

    #pragma unroll
    for (int h = 0; h < HH; ++h) {
        float m = v[h];
        #pragma unroll
        for (int s = 32; s >= 1; s >>= 1) m = fmaxf(m, __shfl_xor(m, s));
        if (lane == 0) red[h][wave] = m;
    }
    __syncthreads();
    float mh[8];
    #pragma unroll
    for (int h = 0; h < HH; ++h) {
        float m = red[h][0];
        #pragma unroll
        for (int w = 1; w < 8; ++w) m = fmaxf(m, red[h][w]);
        mh[h] = m;
    }
    __syncthreads();
    float e[8];
    #pragma unroll
    for (int h = 0; h < HH; ++h) {
        e[h] = __expf(v[h] - mh[h]);
        float s = e[h];
        #pragma unroll
        for (int m = 32; m >= 1; m >>= 1) s += __shfl_xor(s, m);
        if (lane == 0) red[h][wave] = s;
    }
    __syncthreads();
    #pragma unroll
    for (int h = 0; h < HH; ++h) {
        float s = red[h][0] + red[h][1] + red[h][2] + red[h][3]
                + red[h][4] + red[h][5] + red[h][6] + red[h][7];
        e[h] *= (1.f / s);
    }
    float* op = out + (size_t)n * (LL * HH) + (size_t)l * HH;
    float4 p0 = {e[0], e[1], e[2], e[3]};
    float4 p1 = {e[4], e[5], e[6], e[7]};
    *(float4*)(op)     = p0;
    *(float4*)(op + 4) = p1;
}

extern "C" void kernel_launch(void* const* d_in, const int* in_sizes, int n_in,
                              void* d_out, int out_size, void* d_ws, size_t ws_size,
                              hipStream_t stream) {
    (void)in_sizes; (void)n_in; (void)out_size; (void)ws_size;
    const float* msa   = (const float*)d_in[0];
    const float* Wq    = (const float*)d_in[1];
    const float* bq    = (const float*)d_in[2];
    const float* Wk    = (const float*)d_in[3];
    // d_in[4] = bk: per-(l,h) constant in logits -> cancelled by softmax over n.
    const float* gamma = (const float*)d_in[5];
    const float* beta  = (const float*)d_in[6];
    int*   counters = (int*)d_ws;                              // 256 ints
    float* wslog    = (float*)((char*)d_ws + 4096);            // [256][512][8] f32 = 4 MB
    hipMemsetAsync(counters, 0, 256 * sizeof(int), stream);
    k_fused<<<dim3(LL * 2), dim3(512), 0, stream>>>(
        msa, Wq, bq, Wk, gamma, beta, counters, wslog, (float*)d_out);
}

// Round 11
// 41.074 us; speedup vs baseline: 6.0868x; 6.0868x over previous
//
#include <hip/hip_runtime.h>
#include <hip/hip_bf16.h>
#include <cstdint>

#define LL 256   // L
#define NN 512   // N
#define DD 256   // D
#define HH 8
#define EPSF 1e-5f
#define WGS 264  // padded LDS row stride (bf16 elems) for Wg

typedef __attribute__((ext_vector_type(8))) __bf16 bf16x8;
typedef __attribute__((ext_vector_type(4))) float f32x4;

static __device__ __forceinline__ void lb_sync() {
    // barrier WITHOUT vmcnt drain: LDS-publish only; global loads stay in flight
    __builtin_amdgcn_sched_barrier(0);
    asm volatile("s_waitcnt lgkmcnt(0)" ::: "memory");
    __builtin_amdgcn_s_barrier();
    __builtin_amdgcn_sched_barrier(0);
}

static __device__ __forceinline__ void load_group(
    const float* __restrict__ msa, int l, int row0, int col, int kb, float4 (&buf)[16])
{
    const float* rp = msa + ((size_t)(row0 + col) * LL + l) * DD + (kb << 3);
    #pragma unroll
    for (int ks = 0; ks < 8; ++ks) {
        buf[2 * ks]     = *(const float4*)(rp + ks * 32);
        buf[2 * ks + 1] = *(const float4*)(rp + ks * 32 + 4);
    }
}

static __device__ __forceinline__ void compute_group(
    const float4 (&buf)[16], const bf16x8 (&bfr)[8], f32x4& hacc, f32x4& gacc)
{
    #pragma unroll
    for (int ks = 0; ks < 8; ++ks) {
        float4 u = buf[2 * ks], v = buf[2 * ks + 1];
        bf16x8 a;
        a[0] = (__bf16)u.x; a[1] = (__bf16)u.y; a[2] = (__bf16)u.z; a[3] = (__bf16)u.w;
        a[4] = (__bf16)v.x; a[5] = (__bf16)v.y; a[6] = (__bf16)v.z; a[7] = (__bf16)v.w;
        hacc = __builtin_amdgcn_mfma_f32_16x16x32_bf16(a, bfr[ks], hacc, 0, 0, 0);
        gacc = __builtin_amdgcn_mfma_f32_16x16x32_bf16(a, a,       gacc, 0, 0, 0);
    }
}

static __device__ __forceinline__ void store_group(
    int nloc0, int col, int kb, const f32x4& hacc, const f32x4& gacc,
    float* logits, float* sS, float* sQ)
{
    #pragma unroll
    for (int i = 0; i < 4; ++i) {
        int n = nloc0 + (kb << 2) + i;       // C/D: col=lane&15, row=kb*4+i
        if (col < HH)       logits[col * NN + n] = hacc[i];
        else if (col == HH) sS[n] = hacc[i];
    }
    if (kb == (col >> 2)) sQ[nloc0 + col] = gacc[col & 3];   // Gram diagonal
}

__global__ __launch_bounds__(1024, 4) void k_fused(
    const float* __restrict__ msa, const float* __restrict__ Wq,
    const float* __restrict__ bq, const float* __restrict__ Wk,
    const float* __restrict__ gamma, const float* __restrict__ beta,
    float* __restrict__ out)
{
    const int l = blockIdx.x;
    const int tid = threadIdx.x, wave = tid >> 6, lane = tid & 63;
    const int col = lane & 15, kb = lane >> 4;

    __shared__ __align__(16) float logits[HH * NN];  // 16 KB
    __shared__ __align__(16) float sS[NN];           // Σx̂
    __shared__ __align__(16) float sQ[NN];           // Σx̂²
    __shared__ __align__(16) __bf16 WgL[16 * WGS];   // 8.25 KB
    __shared__ __align__(16) float qpart[4][264];    // Wq partials (padded)
    __shared__ float lnx[DD];
    __shared__ float qv[DD];
    __shared__ float red8[8];
    __shared__ float stats[16];
    __shared__ float Gs[HH];

    // ---- prefetch this wave's group-0 rows (n = wave*16 .. +15); overlaps phase 1 ----
    float4 A[16];
    load_group(msa, l, wave * 16, col, kb, A);

    // ---------- Phase 1: Wg = gamma ⊙ (q·Wk) in LDS (1024 threads) ----------
    {
        float x0 = (tid < DD) ? msa[(size_t)l * DD + tid] : 0.f;
        float s = x0, ss = x0 * x0;
        #pragma unroll
        for (int m = 32; m >= 1; m >>= 1) { s += __shfl_xor(s, m); ss += __shfl_xor(ss, m); }
        if (tid < DD && lane == 0) { red8[wave * 2] = s; red8[wave * 2 + 1] = ss; }
        lb_sync();
        if (tid < DD) {
            float sm = red8[0] + red8[2] + red8[4] + red8[6];
            float sq = red8[1] + red8[3] + red8[5] + red8[7];
            float mean = sm * (1.f / DD);
            float var  = sq * (1.f / DD) - mean * mean;
            float rs   = rsqrtf(var + EPSF);
            lnx[tid] = (x0 - mean) * rs * gamma[tid] + beta[tid];
        }
        lb_sync();
        // Wq GEMV: 4-way row split, 1024 tasks: r = tid&255, quarter = tid>>8
        {
            const int r = tid & 255, qtr = tid >> 8;
            const float4* wr = (const float4*)(Wq + (size_t)r * DD) + qtr * 16;
            const float* lx = lnx + qtr * 64;
            float acc = 0.f;
            #pragma unroll 4
            for (int j = 0; j < 16; ++j) {
                float4 w4 = wr[j];
                acc += lx[4*j] * w4.x + lx[4*j+1] * w4.y + lx[4*j+2] * w4.z + lx[4*j+3] * w4.w;
            }
            qpart[qtr][r] = acc;
        }
        lb_sync();
        if (tid < DD)
            qv[tid] = (qpart[0][tid] + qpart[1][tid] + qpart[2][tid] + qpart[3][tid]
                       + bq[tid]) * 0.17677669529663687f;
        lb_sync();
        // Wk GEMV: 2 heads per thread: c = tid&255, h ∈ {tid>>8, (tid>>8)+4}
        {
            const int c = tid & 255, hb = tid >> 8;
            const float gm = gamma[c];
            #pragma unroll
            for (int hi = 0; hi < 2; ++hi) {
                int h = hb + hi * 4;
                float a = 0.f;
                const float* wk = Wk + ((size_t)h * 32) * DD + c;
                #pragma unroll 8
                for (int d = 0; d < 32; ++d)
                    a += qv[h * 32 + d] * wk[(size_t)d * DD];
                WgL[h * WGS + c] = (__bf16)(gm * a);
            }
        }
        if (tid < DD) {
            WgL[8 * WGS + tid] = (__bf16)1.0f;     // ones column -> row sums
            #pragma unroll
            for (int h = 9; h < 16; ++h) WgL[h * WGS + tid] = (__bf16)0.0f;
        }
        lb_sync();
        if (wave < HH) {                           // G[h] = sum_c Wg[h][c]
            float gsum = 0.f;
            #pragma unroll
            for (int i = 0; i < 4; ++i) gsum += (float)WgL[wave * WGS + lane * 4 + i];
            #pragma unroll
            for (int m = 32; m >= 1; m >>= 1) gsum += __shfl_xor(gsum, m);
            if (lane == 0) Gs[wave] = gsum;
        }
        lb_sync();
    }

    // ---------- B fragments ----------
    bf16x8 bfr[8];
    #pragma unroll
    for (int ks = 0; ks < 8; ++ks)
        bfr[ks] = *(const bf16x8*)&WgL[col * WGS + ks * 32 + kb * 8];

    // ---------- Main: 16 waves × 2 groups of 16 rows (512 rows total) ----------
    const f32x4 z = {0.f, 0.f, 0.f, 0.f};
    {
        f32x4 ha = z, ga = z;
        compute_group(A, bfr, ha, ga);
        store_group(wave * 16, col, kb, ha, ga, logits, sS, sQ);
    }
    load_group(msa, l, 256 + wave * 16, col, kb, A);
    {
        f32x4 ha = z, ga = z;
        compute_group(A, bfr, ha, ga);
        store_group(256 + wave * 16, col, kb, ha, ga, logits, sS, sQ);
    }
    lb_sync();

    // ---------- softmax stats: waves 0-7 -> head h=wave over all 512 n ----------
    if (wave < HH) {
        const int h = wave;
        const float Gh = Gs[h];
        const float* lp = logits + h * NN;
        float4 ra = ((const float4*)lp)[lane * 2];
        float4 rb = ((const float4*)lp)[lane * 2 + 1];
        float4 sa = ((const float4*)sS)[lane * 2];
        float4 sb = ((const float4*)sS)[lane * 2 + 1];
        float4 qa = ((const float4*)sQ)[lane * 2];
        float4 qb = ((const float4*)sQ)[lane * 2 + 1];
        float raw[8] = {ra.x, ra.y, ra.z, ra.w, rb.x, rb.y, rb.z, rb.w};
        float sv[8]  = {sa.x, sa.y, sa.z, sa.w, sb.x, sb.y, sb.z, sb.w};
        float qv2[8] = {qa.x, qa.y, qa.z, qa.w, qb.x, qb.y, qb.z, qb.w};
        float adj[8];
        #pragma unroll
        for (int i = 0; i < 8; ++i) {
            float mean = sv[i] * (1.f / DD);
            float var  = qv2[i] * (1.f / DD) - mean * mean;
            float rs   = rsqrtf(var + EPSF);
            adj[i] = rs * (raw[i] - mean * Gh);
        }
        float mx = adj[0];
        #pragma unroll
        for (int i = 1; i < 8; ++i) mx = fmaxf(mx, adj[i]);
        #pragma unroll
        for (int m = 32; m >= 1; m >>= 1) mx = fmaxf(mx, __shfl_xor(mx, m));
        float sm = 0.f;
        #pragma unroll
        for (int i = 0; i < 8; ++i) sm += __expf(adj[i] - mx);
        #pragma unroll
        for (int m = 32; m >= 1; m >>= 1) sm += __shfl_xor(sm, m);
        if (lane == 0) { stats[wave] = mx; stats[8 + wave] = 1.f / sm; }
    }
    lb_sync();

    // ---------- epilogue: thread t<512 -> n=t, 8 heads, fp32 out ----------
    if (tid < NN) {
        const int n = tid;
        float s = sS[n], q2 = sQ[n];
        float mean = s * (1.f / DD);
        float var  = q2 * (1.f / DD) - mean * mean;
        float rs   = rsqrtf(var + EPSF);
        float o[8];
        #pragma unroll
        for (int h = 0; h < HH; ++h) {
            float adj = rs * (logits[h * NN + n] - mean * Gs[h]);
            o[h] = __expf(adj - stats[h]) * stats[8 + h];
        }
        float* op = out + (size_t)n * LL * HH + (size_t)l * HH;
        float4 p0 = {o[0], o[1], o[2], o[3]};
        float4 p1 = {o[4], o[5], o[6], o[7]};
        *(float4*)(op)     = p0;
        *(float4*)(op + 4) = p1;
    }
}

extern "C" void kernel_launch(void* const* d_in, const int* in_sizes, int n_in,
                              void* d_out, int out_size, void* d_ws, size_t ws_size,
                              hipStream_t stream) {
    (void)in_sizes; (void)n_in; (void)out_size; (void)d_ws; (void)ws_size;
    const float* msa   = (const float*)d_in[0];
    const float* Wq    = (const float*)d_in[1];
    const float* bq    = (const float*)d_in[2];
    const float* Wk    = (const float*)d_in[3];
    // d_in[4] = bk: per-(l,h) constant in logits -> cancelled by softmax over n.
    const float* gamma = (const float*)d_in[5];
    const float* beta  = (const float*)d_in[6];
    k_fused<<<dim3(LL), dim3(1024), 0, stream>>>(msa, Wq, bq, Wk, gamma, beta, (float*)d_out);
}